// Round 5
// baseline (1682.422 us; speedup 1.0000x reference)
//
#include <hip/hip_runtime.h>
#include <hip/hip_bf16.h>

#define N_NODES 131072
#define N_EDGES 524288
#define F_IN 16
#define DIM 64
#define DNN 16
#define BK 4
#define NG 8192
#define N_ITERS 8   // NL1*NL2

#define FMA4(A_, S_, W_) { (A_).x = fmaf((S_), (W_).x, (A_).x); (A_).y = fmaf((S_), (W_).y, (A_).y); \
                           (A_).z = fmaf((S_), (W_).z, (A_).z); (A_).w = fmaf((S_), (W_).w, (A_).w); }

// ---------------- degree / inverse count ----------------
__global__ __launch_bounds__(256) void k_degree(const int* __restrict__ ei, float* __restrict__ cnt) {
    int e = blockIdx.x * 256 + threadIdx.x;
    atomicAdd(&cnt[ei[N_EDGES + e]], 1.0f);
}

__global__ __launch_bounds__(256) void k_invcnt(float* __restrict__ cnt) {
    int i = blockIdx.x * 256 + threadIdx.x;
    cnt[i] = 1.0f / fmaxf(cnt[i], 1.0f);
}

// ---------------- prep: transpose weights ----------------
// Wt[j][d][g*64 + cg*4 + jj], d=0..79 (0..15 = wih k, 16..79 = whh d-16), c = g*64 + jj*16 + cg
__global__ __launch_bounds__(256) void k_prep(const float* __restrict__ wih, const float* __restrict__ whh,
                                              const float* __restrict__ w1, float* __restrict__ Wt,
                                              float* __restrict__ w1t) {
    int idx = blockIdx.x * 256 + threadIdx.x;
    if (idx < 4 * 80 * 192) {
        int j = idx / 15360, r = idx % 15360;
        int d = r / 192, col = r % 192;
        int g = col >> 6, rr = col & 63, cgv = rr >> 2, jj = rr & 3;
        int c = g * 64 + jj * 16 + cgv;
        float v = (d < 16) ? wih[(size_t)j * 192 * 16 + c * 16 + d]
                           : whh[(size_t)j * 192 * 64 + c * 64 + (d - 16)];
        Wt[idx] = v;
    }
    if (idx < 1024) {
        int ct = idx >> 6, d = idx & 63;
        w1t[idx] = w1[d * 16 + ct];
    }
}

// ---------------- init: h = relu(x @ lin0_w + lin0_b) ----------------
__global__ __launch_bounds__(256) void k_init(const float* __restrict__ x, const float* __restrict__ w,
                                              const float* __restrict__ b, float* __restrict__ h) {
    __shared__ float s_w[F_IN * DIM];
    int tid = threadIdx.x;
    for (int idx = tid; idx < F_IN * DIM; idx += 256) s_w[idx] = w[idx];
    __syncthreads();
    int gid = blockIdx.x * 256 + tid;
    int i = gid >> 6;
    int c = gid & 63;
    int lane = tid & 63;
    float xv = x[i * F_IN + (lane & 15)];
    float acc = b[c];
#pragma unroll
    for (int k = 0; k < F_IN; ++k) acc += __shfl(xv, k, 64) * s_w[k * DIM + c];
    h[gid] = fmaxf(acc, 0.0f);
}

// ---------------- out1 = h @ lin1_w + lin1_b ; also zero aggr (once, pre-loop) ----------------
__global__ __launch_bounds__(256) void k_lin1(const float* __restrict__ h, const float* __restrict__ w,
                                              const float* __restrict__ b, float* __restrict__ out1,
                                              float* __restrict__ aggr) {
    __shared__ float s_h[64 * 68];
    int tid = threadIdx.x;
    int nb = blockIdx.x * 64;
    const float4* hp = (const float4*)(h + (size_t)nb * 64);
    for (int i = tid; i < 64 * 16; i += 256) {
        int n = i >> 4, q4 = i & 15;
        float4 v = hp[i];
        *(float4*)&s_h[n * 68 + q4 * 4] = v;
    }
    int ct = tid & 15;
    float wcol[64];
#pragma unroll
    for (int q = 0; q < 64; ++q) wcol[q] = w[q * 16 + ct];
    float bias = b[ct];
    ((float4*)(aggr + (size_t)nb * 16))[tid] = make_float4(0.f, 0.f, 0.f, 0.f);
    __syncthreads();
    int ng = tid >> 4;
#pragma unroll
    for (int rep = 0; rep < 4; ++rep) {
        int nl = ng + 16 * rep;
        float acc = bias;
#pragma unroll
        for (int q4 = 0; q4 < 16; ++q4) {
            float4 hv = *(const float4*)&s_h[nl * 68 + q4 * 4];
            acc = fmaf(hv.x, wcol[4 * q4 + 0], acc);
            acc = fmaf(hv.y, wcol[4 * q4 + 1], acc);
            acc = fmaf(hv.z, wcol[4 * q4 + 2], acc);
            acc = fmaf(hv.w, wcol[4 * q4 + 3], acc);
        }
        out1[(size_t)(nb + nl) * 16 + ct] = acc;
    }
}

// ---------------- edge: register-cached W columns, grid-stride over edges ----------------
__global__ __launch_bounds__(256, 3) void k_edge(const float* __restrict__ out1, const float* __restrict__ ea,
                                                 const int* __restrict__ ei, const float* __restrict__ nn1w,
                                                 const float* __restrict__ nn1b, float* __restrict__ aggr) {
    int tid = threadIdx.x;
    int o = tid & 15;
    float w0[16], w1[16], w2[16], w3[16], bs[16];
#pragma unroll
    for (int k = 0; k < 16; ++k) {
        int wi = k * 16 + o;
        bs[k] = nn1b[wi];
        w0[k] = nn1w[wi];
        w1[k] = nn1w[256 + wi];
        w2[k] = nn1w[512 + wi];
        w3[k] = nn1w[768 + wi];
    }
    int eg = blockIdx.x * 16 + (tid >> 4);
    int estride = gridDim.x * 16;
    for (int e = eg; e < N_EDGES; e += estride) {
        int src = ei[e];
        int dst = ei[N_EDGES + e];
        const float4* xp = (const float4*)(out1 + (size_t)src * 16);
        float4 x0 = xp[0], x1 = xp[1], x2 = xp[2], x3 = xp[3];
        float4 a = ((const float4*)ea)[e];
        float xa[16] = {x0.x, x0.y, x0.z, x0.w, x1.x, x1.y, x1.z, x1.w,
                        x2.x, x2.y, x2.z, x2.w, x3.x, x3.y, x3.z, x3.w};
        float msg = 0.f;
#pragma unroll
        for (int k = 0; k < 16; ++k) {
            float wv = bs[k];
            wv = fmaf(a.x, w0[k], wv);
            wv = fmaf(a.y, w1[k], wv);
            wv = fmaf(a.z, w2[k], wv);
            wv = fmaf(a.w, w3[k], wv);
            msg = fmaf(xa[k], wv, msg);
        }
        atomicAdd(&aggr[(size_t)dst * 16 + o], msg);
    }
}

// ---------------- node v3: LDS activations + global(L2) weights + fused lin1 ----------------
// block = 64 nodes, 256 thr = 16 ng x 16 cg; sub-ng = ng&3, wave w = ng>>2
// thread nodes: nl = 16*w + sng + 4*m (m=0..3); cols cg+16j (j=0..3), 3 gates
// s_xh[n][0..15] = out1 then o2 ; s_xh[n][16..79] = h (stride 84 -> sub-ng lanes hit distinct banks)
__global__ __launch_bounds__(256, 3) void k_node(
    float* __restrict__ out1, float* __restrict__ aggr, const float* __restrict__ inv_cnt,
    float* __restrict__ h, const float* __restrict__ Wt, const float* __restrict__ root_w,
    const float* __restrict__ conv_b, const float* __restrict__ bih, const float* __restrict__ bhh,
    const float* __restrict__ w1t, const float* __restrict__ lin1_b)
{
    __shared__ float s_xh[64 * 84];    // 21504 B
    __shared__ float s_w1[16 * 68];    // 4352 B
    int tid = threadIdx.x;
    int nb = blockIdx.x * 64;
    // stage out1 tile (64x16 = 256 float4) and w1t (256 float4)
    {
        float4 v = ((const float4*)(out1 + (size_t)nb * 16))[tid];
        int n = tid >> 2, k4 = tid & 3;
        *(float4*)&s_xh[n * 84 + k4 * 4] = v;
        float4 wv = ((const float4*)w1t)[tid];
        int ct = tid >> 4, d4 = tid & 15;
        *(float4*)&s_w1[ct * 68 + d4 * 4] = wv;
    }
    // stage h tile (64x64 = 1024 float4)
    {
        const float4* hsrc = (const float4*)(h + (size_t)nb * 64);
        for (int i = tid; i < 1024; i += 256) {
            float4 v = hsrc[i];
            int n = i >> 4, d4 = i & 15;
            *(float4*)&s_xh[n * 84 + 16 + d4 * 4] = v;
        }
    }
    int cg = tid & 15, ng = tid >> 4;
    int sng = ng & 3, wq = ng >> 2;
    int nl0 = 16 * wq + sng;           // + 4*m
    float rwv[16];
#pragma unroll
    for (int k = 0; k < 16; ++k) rwv[k] = root_w[k * 16 + cg];
    float cb = conv_b[cg];
    __syncthreads();
    // o2 = out1@root_w + aggr*inv + cb  (reads out1 region); zero aggr for next iter
    float o2v[4];
#pragma unroll
    for (int m = 0; m < 4; ++m) {
        int nl = nl0 + 4 * m, n = nb + nl;
        float acc = fmaf(aggr[(size_t)n * 16 + cg], inv_cnt[n], cb);
        aggr[(size_t)n * 16 + cg] = 0.0f;
#pragma unroll
        for (int k4 = 0; k4 < 4; ++k4) {
            float4 xv = *(const float4*)&s_xh[nl * 84 + k4 * 4];
            acc = fmaf(xv.x, rwv[4 * k4 + 0], acc);
            acc = fmaf(xv.y, rwv[4 * k4 + 1], acc);
            acc = fmaf(xv.z, rwv[4 * k4 + 2], acc);
            acc = fmaf(xv.w, rwv[4 * k4 + 3], acc);
        }
        o2v[m] = acc;
    }
    __syncthreads();
#pragma unroll
    for (int m = 0; m < 4; ++m) s_xh[(nl0 + 4 * m) * 84 + cg] = o2v[m];
    __syncthreads();

    // gates GEMM over concatenated K (d=0..15 -> o2/wih, d=16..79 -> h/whh)
    const float4* Wt4 = (const float4*)Wt;
    float4 ar[4], az[4], ani[4], anh[4];
#pragma unroll
    for (int m = 0; m < 4; ++m) {
        ar[m] = make_float4(0.f, 0.f, 0.f, 0.f);
        az[m] = make_float4(0.f, 0.f, 0.f, 0.f);
        ani[m] = make_float4(0.f, 0.f, 0.f, 0.f);
        anh[m] = make_float4(0.f, 0.f, 0.f, 0.f);
    }
#define GSTEP(D_, XC_, AN_) { \
        float4 w_r = Wt4[(D_) * 48 + cg]; \
        float4 w_z = Wt4[(D_) * 48 + 16 + cg]; \
        float4 w_n = Wt4[(D_) * 48 + 32 + cg]; \
        FMA4(ar[0], xv0.XC_, w_r); FMA4(az[0], xv0.XC_, w_z); FMA4(AN_[0], xv0.XC_, w_n); \
        FMA4(ar[1], xv1.XC_, w_r); FMA4(az[1], xv1.XC_, w_z); FMA4(AN_[1], xv1.XC_, w_n); \
        FMA4(ar[2], xv2.XC_, w_r); FMA4(az[2], xv2.XC_, w_z); FMA4(AN_[2], xv2.XC_, w_n); \
        FMA4(ar[3], xv3.XC_, w_r); FMA4(az[3], xv3.XC_, w_z); FMA4(AN_[3], xv3.XC_, w_n); }
#pragma unroll
    for (int dc = 0; dc < 4; ++dc) {   // ih part -> ani
        float4 xv0 = *(const float4*)&s_xh[(nl0     ) * 84 + dc * 4];
        float4 xv1 = *(const float4*)&s_xh[(nl0 +  4) * 84 + dc * 4];
        float4 xv2 = *(const float4*)&s_xh[(nl0 +  8) * 84 + dc * 4];
        float4 xv3 = *(const float4*)&s_xh[(nl0 + 12) * 84 + dc * 4];
        GSTEP(dc * 4 + 0, x, ani) GSTEP(dc * 4 + 1, y, ani)
        GSTEP(dc * 4 + 2, z, ani) GSTEP(dc * 4 + 3, w, ani)
    }
#pragma unroll 4
    for (int dc = 4; dc < 20; ++dc) {  // hh part -> anh
        float4 xv0 = *(const float4*)&s_xh[(nl0     ) * 84 + dc * 4];
        float4 xv1 = *(const float4*)&s_xh[(nl0 +  4) * 84 + dc * 4];
        float4 xv2 = *(const float4*)&s_xh[(nl0 +  8) * 84 + dc * 4];
        float4 xv3 = *(const float4*)&s_xh[(nl0 + 12) * 84 + dc * 4];
        GSTEP(dc * 4 + 0, x, anh) GSTEP(dc * 4 + 1, y, anh)
        GSTEP(dc * 4 + 2, z, anh) GSTEP(dc * 4 + 3, w, anh)
    }
#undef GSTEP

    // epilogue: GRU elementwise (h_old read from LDS)
    float b_r[4], b_z[4], b_ni[4], b_nh[4];
#pragma unroll
    for (int j = 0; j < 4; ++j) {
        int c = cg + 16 * j;
        b_r[j]  = bih[c] + bhh[c];
        b_z[j]  = bih[64 + c] + bhh[64 + c];
        b_ni[j] = bih[128 + c];
        b_nh[j] = bhh[128 + c];
    }
    float lb1 = lin1_b[cg];
    float hn[4][4];
#define EPI(M_, J_, COMP_) { \
        float rr = 1.0f / (1.0f + __expf(-(ar[M_].COMP_ + b_r[J_]))); \
        float zz = 1.0f / (1.0f + __expf(-(az[M_].COMP_ + b_z[J_]))); \
        float xx = fmaf(rr, anh[M_].COMP_ + b_nh[J_], ani[M_].COMP_ + b_ni[J_]); \
        float axx = fabsf(xx); float ee = __expf(-2.0f * axx); \
        float ncv = __builtin_copysignf((1.0f - ee) / (1.0f + ee), xx); \
        float hold = s_xh[(nl0 + 4 * (M_)) * 84 + 16 + cg + 16 * (J_)]; \
        hn[M_][J_] = fmaf(zz, hold - ncv, ncv); }
#pragma unroll
    for (int m = 0; m < 4; ++m) {
        EPI(m, 0, x) EPI(m, 1, y) EPI(m, 2, z) EPI(m, 3, w)
    }
#undef EPI
    __syncthreads();   // all h_old reads done
#pragma unroll
    for (int m = 0; m < 4; ++m) {
        int nl = nl0 + 4 * m;
#pragma unroll
        for (int j = 0; j < 4; ++j) s_xh[nl * 84 + 16 + cg + 16 * j] = hn[m][j];
    }
    __syncthreads();
    // fused lin1: out1_next = h_new @ w1 + b1
#pragma unroll
    for (int m = 0; m < 4; ++m) {
        int nl = nl0 + 4 * m;
        float acc = lb1;
#pragma unroll
        for (int d4 = 0; d4 < 16; ++d4) {
            float4 hv = *(const float4*)&s_xh[nl * 84 + 16 + d4 * 4];
            float4 wv = *(const float4*)&s_w1[cg * 68 + d4 * 4];
            acc = fmaf(hv.x, wv.x, fmaf(hv.y, wv.y, fmaf(hv.z, wv.z, fmaf(hv.w, wv.w, acc))));
        }
        out1[(size_t)(nb + nl) * 16 + cg] = acc;
    }
    // coalesced h writeback
    {
        float4* hdst = (float4*)(h + (size_t)nb * 64);
        for (int i = tid; i < 1024; i += 256) {
            int n = i >> 4, d4 = i & 15;
            hdst[i] = *(const float4*)&s_xh[n * 84 + 16 + d4 * 4];
        }
    }
}

// ---------------- final: y = h @ lin2_w ; pooled = segment_sum(y, batch) ----------------
__global__ __launch_bounds__(256) void k_final(const float* __restrict__ h, const float* __restrict__ w2,
                                               const int* __restrict__ batch, float* __restrict__ out) {
    int i = blockIdx.x * 4 + (threadIdx.x >> 6);
    int lane = threadIdx.x & 63;
    float v = h[(size_t)i * DIM + lane] * w2[lane];
#pragma unroll
    for (int off = 32; off > 0; off >>= 1) v += __shfl_down(v, off, 64);
    if (lane == 0) atomicAdd(&out[batch[i]], v);
}

extern "C" void kernel_launch(void* const* d_in, const int* in_sizes, int n_in,
                              void* d_out, int out_size, void* d_ws, size_t ws_size,
                              hipStream_t stream) {
    const float* x        = (const float*)d_in[0];
    const float* edge_attr= (const float*)d_in[1];
    const float* lin0_w   = (const float*)d_in[2];
    const float* lin0_b   = (const float*)d_in[3];
    const float* nn1_w    = (const float*)d_in[4];
    const float* nn1_b    = (const float*)d_in[5];
    const float* root_w   = (const float*)d_in[6];
    const float* conv_b   = (const float*)d_in[7];
    const float* gru_w_ih = (const float*)d_in[8];
    const float* gru_w_hh = (const float*)d_in[9];
    const float* gru_b_ih = (const float*)d_in[10];
    const float* gru_b_hh = (const float*)d_in[11];
    const float* lin1_w   = (const float*)d_in[12];
    const float* lin1_b   = (const float*)d_in[13];
    const float* lin2_w   = (const float*)d_in[14];
    const int*   ei       = (const int*)d_in[15];
    const int*   batch    = (const int*)d_in[16];
    float* out = (float*)d_out;

    // ws: h[N*64] | out1[N*16] | aggr[N*16] | inv_cnt[N] | Wt[4*80*192] | w1t[1024]
    char* ws = (char*)d_ws;
    float* h       = (float*)(ws);
    float* out1    = (float*)(ws + (size_t)N_NODES * DIM * 4);
    float* aggr    = (float*)(ws + (size_t)N_NODES * DIM * 4 + (size_t)N_NODES * DNN * 4);
    float* inv_cnt = (float*)(ws + (size_t)N_NODES * DIM * 4 + 2ull * N_NODES * DNN * 4);
    float* Wt      = inv_cnt + N_NODES;
    float* w1t     = Wt + 4 * 80 * 192;

    hipMemsetAsync(d_out, 0, (size_t)NG * 4, stream);
    hipMemsetAsync(inv_cnt, 0, (size_t)N_NODES * 4, stream);
    k_prep<<<240, 256, 0, stream>>>(gru_w_ih, gru_w_hh, lin1_w, Wt, w1t);
    k_degree<<<N_EDGES / 256, 256, 0, stream>>>(ei, inv_cnt);
    k_invcnt<<<N_NODES / 256, 256, 0, stream>>>(inv_cnt);
    k_init<<<N_NODES * DIM / 256, 256, 0, stream>>>(x, lin0_w, lin0_b, h);
    k_lin1<<<N_NODES / 64, 256, 0, stream>>>(h, lin1_w, lin1_b, out1, aggr);

    for (int it = 0; it < N_ITERS; ++it) {
        int j = it >> 1;   // GRU index (NL2 = 2)
        k_edge<<<2048, 256, 0, stream>>>(out1, edge_attr, ei, nn1_w, nn1_b, aggr);
        k_node<<<N_NODES / 64, 256, 0, stream>>>(out1, aggr, inv_cnt, h,
                                                 Wt + (size_t)j * 80 * 192, root_w, conv_b,
                                                 gru_b_ih + (size_t)j * 192,
                                                 gru_b_hh + (size_t)j * 192,
                                                 w1t, lin1_b);
    }
    k_final<<<N_NODES / 4, 256, 0, stream>>>(h, lin2_w, batch, out);
}

// Round 6
// 1340.272 us; speedup vs baseline: 1.2553x; 1.2553x over previous
//
#include <hip/hip_runtime.h>
#include <hip/hip_bf16.h>

#define N_NODES 131072
#define N_EDGES 524288
#define F_IN 16
#define DIM 64
#define DNN 16
#define BK 4
#define NG 8192
#define N_ITERS 8   // NL1*NL2

#define FMA4(A_, S_, W_) { (A_).x = fmaf((S_), (W_).x, (A_).x); (A_).y = fmaf((S_), (W_).y, (A_).y); \
                           (A_).z = fmaf((S_), (W_).z, (A_).z); (A_).w = fmaf((S_), (W_).w, (A_).w); }

// ---------------- degree / inverse count ----------------
__global__ __launch_bounds__(256) void k_degree(const int* __restrict__ ei, float* __restrict__ cnt) {
    int e = blockIdx.x * 256 + threadIdx.x;
    atomicAdd(&cnt[ei[N_EDGES + e]], 1.0f);
}

__global__ __launch_bounds__(256) void k_invcnt(float* __restrict__ cnt) {
    int i = blockIdx.x * 256 + threadIdx.x;
    cnt[i] = 1.0f / fmaxf(cnt[i], 1.0f);
}

// ---------------- prep: transpose weights ----------------
// Wt[j][d][g*64 + cg*4 + jj], d=0..79 (0..15 = wih k, 16..79 = whh d-16), c = g*64 + jj*16 + cg
__global__ __launch_bounds__(256) void k_prep(const float* __restrict__ wih, const float* __restrict__ whh,
                                              const float* __restrict__ w1, float* __restrict__ Wt,
                                              float* __restrict__ w1t) {
    int idx = blockIdx.x * 256 + threadIdx.x;
    if (idx < 4 * 80 * 192) {
        int j = idx / 15360, r = idx % 15360;
        int d = r / 192, col = r % 192;
        int g = col >> 6, rr = col & 63, cgv = rr >> 2, jj = rr & 3;
        int c = g * 64 + jj * 16 + cgv;
        float v = (d < 16) ? wih[(size_t)j * 192 * 16 + c * 16 + d]
                           : whh[(size_t)j * 192 * 64 + c * 64 + (d - 16)];
        Wt[idx] = v;
    }
    if (idx < 1024) {
        int ct = idx >> 6, d = idx & 63;
        w1t[idx] = w1[d * 16 + ct];
    }
}

// ---------------- init: h = relu(x @ lin0_w + lin0_b) ----------------
__global__ __launch_bounds__(256) void k_init(const float* __restrict__ x, const float* __restrict__ w,
                                              const float* __restrict__ b, float* __restrict__ h) {
    __shared__ float s_w[F_IN * DIM];
    int tid = threadIdx.x;
    for (int idx = tid; idx < F_IN * DIM; idx += 256) s_w[idx] = w[idx];
    __syncthreads();
    int gid = blockIdx.x * 256 + tid;
    int i = gid >> 6;
    int c = gid & 63;
    int lane = tid & 63;
    float xv = x[i * F_IN + (lane & 15)];
    float acc = b[c];
#pragma unroll
    for (int k = 0; k < F_IN; ++k) acc += __shfl(xv, k, 64) * s_w[k * DIM + c];
    h[gid] = fmaxf(acc, 0.0f);
}

// ---------------- out1 = h @ lin1_w + lin1_b ; also zero aggr (once, pre-loop) ----------------
__global__ __launch_bounds__(256) void k_lin1(const float* __restrict__ h, const float* __restrict__ w,
                                              const float* __restrict__ b, float* __restrict__ out1,
                                              float* __restrict__ aggr) {
    __shared__ float s_h[64 * 68];
    int tid = threadIdx.x;
    int nb = blockIdx.x * 64;
    const float4* hp = (const float4*)(h + (size_t)nb * 64);
    for (int i = tid; i < 64 * 16; i += 256) {
        int n = i >> 4, q4 = i & 15;
        float4 v = hp[i];
        *(float4*)&s_h[n * 68 + q4 * 4] = v;
    }
    int ct = tid & 15;
    float wcol[64];
#pragma unroll
    for (int q = 0; q < 64; ++q) wcol[q] = w[q * 16 + ct];
    float bias = b[ct];
    ((float4*)(aggr + (size_t)nb * 16))[tid] = make_float4(0.f, 0.f, 0.f, 0.f);
    __syncthreads();
    int ng = tid >> 4;
#pragma unroll
    for (int rep = 0; rep < 4; ++rep) {
        int nl = ng + 16 * rep;
        float acc = bias;
#pragma unroll
        for (int q4 = 0; q4 < 16; ++q4) {
            float4 hv = *(const float4*)&s_h[nl * 68 + q4 * 4];
            acc = fmaf(hv.x, wcol[4 * q4 + 0], acc);
            acc = fmaf(hv.y, wcol[4 * q4 + 1], acc);
            acc = fmaf(hv.z, wcol[4 * q4 + 2], acc);
            acc = fmaf(hv.w, wcol[4 * q4 + 3], acc);
        }
        out1[(size_t)(nb + nl) * 16 + ct] = acc;
    }
}

// ---------------- edge: register-cached W columns, grid-stride over edges ----------------
__attribute__((amdgpu_waves_per_eu(2, 4)))
__global__ __launch_bounds__(256) void k_edge(const float* __restrict__ out1, const float* __restrict__ ea,
                                              const int* __restrict__ ei, const float* __restrict__ nn1w,
                                              const float* __restrict__ nn1b, float* __restrict__ aggr) {
    int tid = threadIdx.x;
    int o = tid & 15;
    float w0[16], w1[16], w2[16], w3[16], bs[16];
#pragma unroll
    for (int k = 0; k < 16; ++k) {
        int wi = k * 16 + o;
        bs[k] = nn1b[wi];
        w0[k] = nn1w[wi];
        w1[k] = nn1w[256 + wi];
        w2[k] = nn1w[512 + wi];
        w3[k] = nn1w[768 + wi];
    }
    int eg = blockIdx.x * 16 + (tid >> 4);
    int estride = gridDim.x * 16;
    for (int e = eg; e < N_EDGES; e += estride) {
        int src = ei[e];
        int dst = ei[N_EDGES + e];
        const float4* xp = (const float4*)(out1 + (size_t)src * 16);
        float4 x0 = xp[0], x1 = xp[1], x2 = xp[2], x3 = xp[3];
        float4 a = ((const float4*)ea)[e];
        float xa[16] = {x0.x, x0.y, x0.z, x0.w, x1.x, x1.y, x1.z, x1.w,
                        x2.x, x2.y, x2.z, x2.w, x3.x, x3.y, x3.z, x3.w};
        float msg = 0.f;
#pragma unroll
        for (int k = 0; k < 16; ++k) {
            float wv = bs[k];
            wv = fmaf(a.x, w0[k], wv);
            wv = fmaf(a.y, w1[k], wv);
            wv = fmaf(a.z, w2[k], wv);
            wv = fmaf(a.w, w3[k], wv);
            msg = fmaf(xa[k], wv, msg);
        }
        atomicAdd(&aggr[(size_t)dst * 16 + o], msg);
    }
}

// ---------------- node v3: LDS activations + global(L2) weights + fused lin1 ----------------
// block = 64 nodes, 256 thr = 16 ng x 16 cg; sub-ng = ng&3, wave w = ng>>2
// thread nodes: nl = 16*w + sng + 4*m (m=0..3); cols cg+16j (j=0..3), 3 gates
// s_xh[n][0..15] = out1 then o2 ; s_xh[n][16..79] = h (stride 84)
// amdgpu_waves_per_eu(2,4): pin VGPR budget at 128 so the compiler does NOT
// spill accumulators to reach the LDS-derived 6-wave occupancy ceiling (R5 bug:
// VGPR=84=512/6, 190MB/dispatch scratch traffic).
__attribute__((amdgpu_waves_per_eu(2, 4)))
__global__ __launch_bounds__(256) void k_node(
    float* __restrict__ out1, float* __restrict__ aggr, const float* __restrict__ inv_cnt,
    float* __restrict__ h, const float* __restrict__ Wt, const float* __restrict__ root_w,
    const float* __restrict__ conv_b, const float* __restrict__ bih, const float* __restrict__ bhh,
    const float* __restrict__ w1t, const float* __restrict__ lin1_b)
{
    __shared__ float s_xh[64 * 84];    // 21504 B
    __shared__ float s_w1[16 * 68];    // 4352 B
    int tid = threadIdx.x;
    int nb = blockIdx.x * 64;
    // stage out1 tile (64x16 = 256 float4) and w1t (256 float4)
    {
        float4 v = ((const float4*)(out1 + (size_t)nb * 16))[tid];
        int n = tid >> 2, k4 = tid & 3;
        *(float4*)&s_xh[n * 84 + k4 * 4] = v;
        float4 wv = ((const float4*)w1t)[tid];
        int ct = tid >> 4, d4 = tid & 15;
        *(float4*)&s_w1[ct * 68 + d4 * 4] = wv;
    }
    // stage h tile (64x64 = 1024 float4)
    {
        const float4* hsrc = (const float4*)(h + (size_t)nb * 64);
        for (int i = tid; i < 1024; i += 256) {
            float4 v = hsrc[i];
            int n = i >> 4, d4 = i & 15;
            *(float4*)&s_xh[n * 84 + 16 + d4 * 4] = v;
        }
    }
    int cg = tid & 15, ng = tid >> 4;
    int sng = ng & 3, wq = ng >> 2;
    int nl0 = 16 * wq + sng;           // + 4*m
    float rwv[16];
#pragma unroll
    for (int k = 0; k < 16; ++k) rwv[k] = root_w[k * 16 + cg];
    float cb = conv_b[cg];
    __syncthreads();
    // o2 = out1@root_w + aggr*inv + cb  (reads out1 region); zero aggr for next iter
    float o2v[4];
#pragma unroll
    for (int m = 0; m < 4; ++m) {
        int nl = nl0 + 4 * m, n = nb + nl;
        float acc = fmaf(aggr[(size_t)n * 16 + cg], inv_cnt[n], cb);
        aggr[(size_t)n * 16 + cg] = 0.0f;
#pragma unroll
        for (int k4 = 0; k4 < 4; ++k4) {
            float4 xv = *(const float4*)&s_xh[nl * 84 + k4 * 4];
            acc = fmaf(xv.x, rwv[4 * k4 + 0], acc);
            acc = fmaf(xv.y, rwv[4 * k4 + 1], acc);
            acc = fmaf(xv.z, rwv[4 * k4 + 2], acc);
            acc = fmaf(xv.w, rwv[4 * k4 + 3], acc);
        }
        o2v[m] = acc;
    }
    __syncthreads();
#pragma unroll
    for (int m = 0; m < 4; ++m) s_xh[(nl0 + 4 * m) * 84 + cg] = o2v[m];
    __syncthreads();

    // gates GEMM over concatenated K (d=0..15 -> o2/wih, d=16..79 -> h/whh)
    const float4* Wt4 = (const float4*)Wt;
    float4 ar[4], az[4], ani[4], anh[4];
#pragma unroll
    for (int m = 0; m < 4; ++m) {
        ar[m] = make_float4(0.f, 0.f, 0.f, 0.f);
        az[m] = make_float4(0.f, 0.f, 0.f, 0.f);
        ani[m] = make_float4(0.f, 0.f, 0.f, 0.f);
        anh[m] = make_float4(0.f, 0.f, 0.f, 0.f);
    }
#define GSTEP(D_, XC_, AN_) { \
        float4 w_r = Wt4[(D_) * 48 + cg]; \
        float4 w_z = Wt4[(D_) * 48 + 16 + cg]; \
        float4 w_n = Wt4[(D_) * 48 + 32 + cg]; \
        FMA4(ar[0], xv0.XC_, w_r); FMA4(az[0], xv0.XC_, w_z); FMA4(AN_[0], xv0.XC_, w_n); \
        FMA4(ar[1], xv1.XC_, w_r); FMA4(az[1], xv1.XC_, w_z); FMA4(AN_[1], xv1.XC_, w_n); \
        FMA4(ar[2], xv2.XC_, w_r); FMA4(az[2], xv2.XC_, w_z); FMA4(AN_[2], xv2.XC_, w_n); \
        FMA4(ar[3], xv3.XC_, w_r); FMA4(az[3], xv3.XC_, w_z); FMA4(AN_[3], xv3.XC_, w_n); }
#pragma unroll
    for (int dc = 0; dc < 4; ++dc) {   // ih part -> ani
        float4 xv0 = *(const float4*)&s_xh[(nl0     ) * 84 + dc * 4];
        float4 xv1 = *(const float4*)&s_xh[(nl0 +  4) * 84 + dc * 4];
        float4 xv2 = *(const float4*)&s_xh[(nl0 +  8) * 84 + dc * 4];
        float4 xv3 = *(const float4*)&s_xh[(nl0 + 12) * 84 + dc * 4];
        GSTEP(dc * 4 + 0, x, ani) GSTEP(dc * 4 + 1, y, ani)
        GSTEP(dc * 4 + 2, z, ani) GSTEP(dc * 4 + 3, w, ani)
    }
#pragma unroll 2
    for (int dc = 4; dc < 20; ++dc) {  // hh part -> anh
        float4 xv0 = *(const float4*)&s_xh[(nl0     ) * 84 + dc * 4];
        float4 xv1 = *(const float4*)&s_xh[(nl0 +  4) * 84 + dc * 4];
        float4 xv2 = *(const float4*)&s_xh[(nl0 +  8) * 84 + dc * 4];
        float4 xv3 = *(const float4*)&s_xh[(nl0 + 12) * 84 + dc * 4];
        GSTEP(dc * 4 + 0, x, anh) GSTEP(dc * 4 + 1, y, anh)
        GSTEP(dc * 4 + 2, z, anh) GSTEP(dc * 4 + 3, w, anh)
    }
#undef GSTEP

    // epilogue: GRU elementwise (h_old read from LDS)
    float b_r[4], b_z[4], b_ni[4], b_nh[4];
#pragma unroll
    for (int j = 0; j < 4; ++j) {
        int c = cg + 16 * j;
        b_r[j]  = bih[c] + bhh[c];
        b_z[j]  = bih[64 + c] + bhh[64 + c];
        b_ni[j] = bih[128 + c];
        b_nh[j] = bhh[128 + c];
    }
    float lb1 = lin1_b[cg];
    float hn[4][4];
#define EPI(M_, J_, COMP_) { \
        float rr = 1.0f / (1.0f + __expf(-(ar[M_].COMP_ + b_r[J_]))); \
        float zz = 1.0f / (1.0f + __expf(-(az[M_].COMP_ + b_z[J_]))); \
        float xx = fmaf(rr, anh[M_].COMP_ + b_nh[J_], ani[M_].COMP_ + b_ni[J_]); \
        float axx = fabsf(xx); float ee = __expf(-2.0f * axx); \
        float ncv = __builtin_copysignf((1.0f - ee) / (1.0f + ee), xx); \
        float hold = s_xh[(nl0 + 4 * (M_)) * 84 + 16 + cg + 16 * (J_)]; \
        hn[M_][J_] = fmaf(zz, hold - ncv, ncv); }
#pragma unroll
    for (int m = 0; m < 4; ++m) {
        EPI(m, 0, x) EPI(m, 1, y) EPI(m, 2, z) EPI(m, 3, w)
    }
#undef EPI
    __syncthreads();   // all h_old reads done
#pragma unroll
    for (int m = 0; m < 4; ++m) {
        int nl = nl0 + 4 * m;
#pragma unroll
        for (int j = 0; j < 4; ++j) s_xh[nl * 84 + 16 + cg + 16 * j] = hn[m][j];
    }
    __syncthreads();
    // fused lin1: out1_next = h_new @ w1 + b1
#pragma unroll
    for (int m = 0; m < 4; ++m) {
        int nl = nl0 + 4 * m;
        float acc = lb1;
#pragma unroll
        for (int d4 = 0; d4 < 16; ++d4) {
            float4 hv = *(const float4*)&s_xh[nl * 84 + 16 + d4 * 4];
            float4 wv = *(const float4*)&s_w1[cg * 68 + d4 * 4];
            acc = fmaf(hv.x, wv.x, fmaf(hv.y, wv.y, fmaf(hv.z, wv.z, fmaf(hv.w, wv.w, acc))));
        }
        out1[(size_t)(nb + nl) * 16 + cg] = acc;
    }
    // coalesced h writeback
    {
        float4* hdst = (float4*)(h + (size_t)nb * 64);
        for (int i = tid; i < 1024; i += 256) {
            int n = i >> 4, d4 = i & 15;
            hdst[i] = *(const float4*)&s_xh[n * 84 + 16 + d4 * 4];
        }
    }
}

// ---------------- final: y = h @ lin2_w ; pooled = segment_sum(y, batch) ----------------
__global__ __launch_bounds__(256) void k_final(const float* __restrict__ h, const float* __restrict__ w2,
                                               const int* __restrict__ batch, float* __restrict__ out) {
    int i = blockIdx.x * 4 + (threadIdx.x >> 6);
    int lane = threadIdx.x & 63;
    float v = h[(size_t)i * DIM + lane] * w2[lane];
#pragma unroll
    for (int off = 32; off > 0; off >>= 1) v += __shfl_down(v, off, 64);
    if (lane == 0) atomicAdd(&out[batch[i]], v);
}

extern "C" void kernel_launch(void* const* d_in, const int* in_sizes, int n_in,
                              void* d_out, int out_size, void* d_ws, size_t ws_size,
                              hipStream_t stream) {
    const float* x        = (const float*)d_in[0];
    const float* edge_attr= (const float*)d_in[1];
    const float* lin0_w   = (const float*)d_in[2];
    const float* lin0_b   = (const float*)d_in[3];
    const float* nn1_w    = (const float*)d_in[4];
    const float* nn1_b    = (const float*)d_in[5];
    const float* root_w   = (const float*)d_in[6];
    const float* conv_b   = (const float*)d_in[7];
    const float* gru_w_ih = (const float*)d_in[8];
    const float* gru_w_hh = (const float*)d_in[9];
    const float* gru_b_ih = (const float*)d_in[10];
    const float* gru_b_hh = (const float*)d_in[11];
    const float* lin1_w   = (const float*)d_in[12];
    const float* lin1_b   = (const float*)d_in[13];
    const float* lin2_w   = (const float*)d_in[14];
    const int*   ei       = (const int*)d_in[15];
    const int*   batch    = (const int*)d_in[16];
    float* out = (float*)d_out;

    // ws: h[N*64] | out1[N*16] | aggr[N*16] | inv_cnt[N] | Wt[4*80*192] | w1t[1024]
    char* ws = (char*)d_ws;
    float* h       = (float*)(ws);
    float* out1    = (float*)(ws + (size_t)N_NODES * DIM * 4);
    float* aggr    = (float*)(ws + (size_t)N_NODES * DIM * 4 + (size_t)N_NODES * DNN * 4);
    float* inv_cnt = (float*)(ws + (size_t)N_NODES * DIM * 4 + 2ull * N_NODES * DNN * 4);
    float* Wt      = inv_cnt + N_NODES;
    float* w1t     = Wt + 4 * 80 * 192;

    hipMemsetAsync(d_out, 0, (size_t)NG * 4, stream);
    hipMemsetAsync(inv_cnt, 0, (size_t)N_NODES * 4, stream);
    k_prep<<<240, 256, 0, stream>>>(gru_w_ih, gru_w_hh, lin1_w, Wt, w1t);
    k_degree<<<N_EDGES / 256, 256, 0, stream>>>(ei, inv_cnt);
    k_invcnt<<<N_NODES / 256, 256, 0, stream>>>(inv_cnt);
    k_init<<<N_NODES * DIM / 256, 256, 0, stream>>>(x, lin0_w, lin0_b, h);
    k_lin1<<<N_NODES / 64, 256, 0, stream>>>(h, lin1_w, lin1_b, out1, aggr);

    for (int it = 0; it < N_ITERS; ++it) {
        int j = it >> 1;   // GRU index (NL2 = 2)
        k_edge<<<2048, 256, 0, stream>>>(out1, edge_attr, ei, nn1_w, nn1_b, aggr);
        k_node<<<N_NODES / 64, 256, 0, stream>>>(out1, aggr, inv_cnt, h,
                                                 Wt + (size_t)j * 80 * 192, root_w, conv_b,
                                                 gru_b_ih + (size_t)j * 192,
                                                 gru_b_hh + (size_t)j * 192,
                                                 w1t, lin1_b);
    }
    k_final<<<N_NODES / 4, 256, 0, stream>>>(h, lin2_w, batch, out);
}

// Round 7
// 1186.422 us; speedup vs baseline: 1.4181x; 1.1297x over previous
//
#include <hip/hip_runtime.h>
#include <hip/hip_bf16.h>

#define N_NODES 131072
#define N_EDGES 524288
#define F_IN 16
#define DIM 64
#define DNN 16
#define BK 4
#define NG 8192
#define N_ITERS 8   // NL1*NL2

#define FMA4(A_, S_, W_) { (A_).x = fmaf((S_), (W_).x, (A_).x); (A_).y = fmaf((S_), (W_).y, (A_).y); \
                           (A_).z = fmaf((S_), (W_).z, (A_).z); (A_).w = fmaf((S_), (W_).w, (A_).w); }

// ---------------- degree / inverse count ----------------
__global__ __launch_bounds__(256) void k_degree(const int* __restrict__ ei, float* __restrict__ cnt) {
    int e = blockIdx.x * 256 + threadIdx.x;
    atomicAdd(&cnt[ei[N_EDGES + e]], 1.0f);
}

__global__ __launch_bounds__(256) void k_invcnt(float* __restrict__ cnt) {
    int i = blockIdx.x * 256 + threadIdx.x;
    cnt[i] = 1.0f / fmaxf(cnt[i], 1.0f);
}

// ---------------- prep: transpose weights ----------------
// Wt[j][d][g*64 + cg*4 + jj], d=0..79 (0..15 = wih k, 16..79 = whh d-16), c = g*64 + jj*16 + cg
__global__ __launch_bounds__(256) void k_prep(const float* __restrict__ wih, const float* __restrict__ whh,
                                              const float* __restrict__ w1, float* __restrict__ Wt,
                                              float* __restrict__ w1t) {
    int idx = blockIdx.x * 256 + threadIdx.x;
    if (idx < 4 * 80 * 192) {
        int j = idx / 15360, r = idx % 15360;
        int d = r / 192, col = r % 192;
        int g = col >> 6, rr = col & 63, cgv = rr >> 2, jj = rr & 3;
        int c = g * 64 + jj * 16 + cgv;
        float v = (d < 16) ? wih[(size_t)j * 192 * 16 + c * 16 + d]
                           : whh[(size_t)j * 192 * 64 + c * 64 + (d - 16)];
        Wt[idx] = v;
    }
    if (idx < 1024) {
        int ct = idx >> 6, d = idx & 63;
        w1t[idx] = w1[d * 16 + ct];
    }
}

// ---------------- init: h = relu(x @ lin0_w + lin0_b) ----------------
__global__ __launch_bounds__(256) void k_init(const float* __restrict__ x, const float* __restrict__ w,
                                              const float* __restrict__ b, float* __restrict__ h) {
    __shared__ float s_w[F_IN * DIM];
    int tid = threadIdx.x;
    for (int idx = tid; idx < F_IN * DIM; idx += 256) s_w[idx] = w[idx];
    __syncthreads();
    int gid = blockIdx.x * 256 + tid;
    int i = gid >> 6;
    int c = gid & 63;
    int lane = tid & 63;
    float xv = x[i * F_IN + (lane & 15)];
    float acc = b[c];
#pragma unroll
    for (int k = 0; k < F_IN; ++k) acc += __shfl(xv, k, 64) * s_w[k * DIM + c];
    h[gid] = fmaxf(acc, 0.0f);
}

// ---------------- out1 = h @ lin1_w + lin1_b ; also zero aggr (once, pre-loop) ----------------
__global__ __launch_bounds__(256) void k_lin1(const float* __restrict__ h, const float* __restrict__ w,
                                              const float* __restrict__ b, float* __restrict__ out1,
                                              float* __restrict__ aggr) {
    __shared__ float s_h[64 * 68];
    int tid = threadIdx.x;
    int nb = blockIdx.x * 64;
    const float4* hp = (const float4*)(h + (size_t)nb * 64);
    for (int i = tid; i < 64 * 16; i += 256) {
        int n = i >> 4, q4 = i & 15;
        float4 v = hp[i];
        *(float4*)&s_h[n * 68 + q4 * 4] = v;
    }
    int ct = tid & 15;
    float wcol[64];
#pragma unroll
    for (int q = 0; q < 64; ++q) wcol[q] = w[q * 16 + ct];
    float bias = b[ct];
    ((float4*)(aggr + (size_t)nb * 16))[tid] = make_float4(0.f, 0.f, 0.f, 0.f);
    __syncthreads();
    int ng = tid >> 4;
#pragma unroll
    for (int rep = 0; rep < 4; ++rep) {
        int nl = ng + 16 * rep;
        float acc = bias;
#pragma unroll
        for (int q4 = 0; q4 < 16; ++q4) {
            float4 hv = *(const float4*)&s_h[nl * 68 + q4 * 4];
            acc = fmaf(hv.x, wcol[4 * q4 + 0], acc);
            acc = fmaf(hv.y, wcol[4 * q4 + 1], acc);
            acc = fmaf(hv.z, wcol[4 * q4 + 2], acc);
            acc = fmaf(hv.w, wcol[4 * q4 + 3], acc);
        }
        out1[(size_t)(nb + nl) * 16 + ct] = acc;
    }
}

// ---------------- edge: register-cached W columns, grid-stride over edges ----------------
__attribute__((amdgpu_waves_per_eu(2, 4)))
__global__ __launch_bounds__(256) void k_edge(const float* __restrict__ out1, const float* __restrict__ ea,
                                              const int* __restrict__ ei, const float* __restrict__ nn1w,
                                              const float* __restrict__ nn1b, float* __restrict__ aggr) {
    int tid = threadIdx.x;
    int o = tid & 15;
    float w0[16], w1[16], w2[16], w3[16], bs[16];
#pragma unroll
    for (int k = 0; k < 16; ++k) {
        int wi = k * 16 + o;
        bs[k] = nn1b[wi];
        w0[k] = nn1w[wi];
        w1[k] = nn1w[256 + wi];
        w2[k] = nn1w[512 + wi];
        w3[k] = nn1w[768 + wi];
    }
    int eg = blockIdx.x * 16 + (tid >> 4);
    int estride = gridDim.x * 16;
    for (int e = eg; e < N_EDGES; e += estride) {
        int src = ei[e];
        int dst = ei[N_EDGES + e];
        const float4* xp = (const float4*)(out1 + (size_t)src * 16);
        float4 x0 = xp[0], x1 = xp[1], x2 = xp[2], x3 = xp[3];
        float4 a = ((const float4*)ea)[e];
        float xa[16] = {x0.x, x0.y, x0.z, x0.w, x1.x, x1.y, x1.z, x1.w,
                        x2.x, x2.y, x2.z, x2.w, x3.x, x3.y, x3.z, x3.w};
        float msg = 0.f;
#pragma unroll
        for (int k = 0; k < 16; ++k) {
            float wv = bs[k];
            wv = fmaf(a.x, w0[k], wv);
            wv = fmaf(a.y, w1[k], wv);
            wv = fmaf(a.z, w2[k], wv);
            wv = fmaf(a.w, w3[k], wv);
            msg = fmaf(xa[k], wv, msg);
        }
        atomicAdd(&aggr[(size_t)dst * 16 + o], msg);
    }
}

// ---------------- node v4: weights AND activations in LDS ----------------
// block = 32 nodes, 256 thr = 16 ng x 16 cg; sng = ng&3, wave wq = ng>>2
// thread nodes: nl = 8*wq + sng + 4*m (m=0..1); cols cg+16j (j=0..3), 3 gates
// s_xh[n][0..15] = out1 then o2 ; s_xh[n][16..79] = h (stride 84)
// s_W = linear Wt tile [80][192] (61.4KB); reads are 16-addr broadcast, 2-way bank (free)
// LDS total 76.5KB -> 2 blocks/CU; waves_per_eu(2,4) pins VGPR<=128 (no spill; R5 lesson)
__attribute__((amdgpu_waves_per_eu(2, 4)))
__global__ __launch_bounds__(256) void k_node(
    float* __restrict__ out1, float* __restrict__ aggr, const float* __restrict__ inv_cnt,
    float* __restrict__ h, const float* __restrict__ Wt, const float* __restrict__ root_w,
    const float* __restrict__ conv_b, const float* __restrict__ bih, const float* __restrict__ bhh,
    const float* __restrict__ w1t, const float* __restrict__ lin1_b)
{
    __shared__ float s_W[80 * 192];    // 61440 B
    __shared__ float s_xh[32 * 84];    // 10752 B
    __shared__ float s_w1[16 * 68];    //  4352 B
    int tid = threadIdx.x;
    int nb = blockIdx.x * 32;
    // stage weights (3840 float4), w1t (256 float4), out1 tile (128 float4), h tile (512 float4)
    {
        const float4* wsrc = (const float4*)Wt;
        float4* wdst = (float4*)s_W;
#pragma unroll
        for (int i = 0; i < 15; ++i) wdst[tid + 256 * i] = wsrc[tid + 256 * i];
        float4 wv = ((const float4*)w1t)[tid];
        int ct = tid >> 4, d4 = tid & 15;
        *(float4*)&s_w1[ct * 68 + d4 * 4] = wv;
        if (tid < 128) {
            float4 v = ((const float4*)(out1 + (size_t)nb * 16))[tid];
            int n = tid >> 2, k4 = tid & 3;
            *(float4*)&s_xh[n * 84 + k4 * 4] = v;
        }
        const float4* hsrc = (const float4*)(h + (size_t)nb * 64);
#pragma unroll
        for (int ii = 0; ii < 2; ++ii) {
            int i = tid + 256 * ii;
            float4 v = hsrc[i];
            int n = i >> 4, d4b = i & 15;
            *(float4*)&s_xh[n * 84 + 16 + d4b * 4] = v;
        }
    }
    int cg = tid & 15, ng = tid >> 4;
    int sng = ng & 3, wq = ng >> 2;
    int nl0 = 8 * wq + sng;            // + 4*m, m=0..1
    float rwv[16];
#pragma unroll
    for (int k = 0; k < 16; ++k) rwv[k] = root_w[k * 16 + cg];
    float cb = conv_b[cg];
    __syncthreads();
    // o2 = out1@root_w + aggr*inv + cb ; zero aggr for next iter
    float o2v[2];
#pragma unroll
    for (int m = 0; m < 2; ++m) {
        int nl = nl0 + 4 * m, n = nb + nl;
        float acc = fmaf(aggr[(size_t)n * 16 + cg], inv_cnt[n], cb);
        aggr[(size_t)n * 16 + cg] = 0.0f;
#pragma unroll
        for (int k4 = 0; k4 < 4; ++k4) {
            float4 xv = *(const float4*)&s_xh[nl * 84 + k4 * 4];
            acc = fmaf(xv.x, rwv[4 * k4 + 0], acc);
            acc = fmaf(xv.y, rwv[4 * k4 + 1], acc);
            acc = fmaf(xv.z, rwv[4 * k4 + 2], acc);
            acc = fmaf(xv.w, rwv[4 * k4 + 3], acc);
        }
        o2v[m] = acc;
    }
    __syncthreads();
#pragma unroll
    for (int m = 0; m < 2; ++m) s_xh[(nl0 + 4 * m) * 84 + cg] = o2v[m];
    __syncthreads();

    // gates GEMM over concatenated K (d=0..15 -> o2/wih, d=16..79 -> h/whh)
    float4 ar[2], az[2], ani[2], anh[2];
#pragma unroll
    for (int m = 0; m < 2; ++m) {
        ar[m] = make_float4(0.f, 0.f, 0.f, 0.f);
        az[m] = make_float4(0.f, 0.f, 0.f, 0.f);
        ani[m] = make_float4(0.f, 0.f, 0.f, 0.f);
        anh[m] = make_float4(0.f, 0.f, 0.f, 0.f);
    }
#define GSTEP(D_, XC_, AN_) { \
        float4 w_r = *(const float4*)&s_W[((D_) * 48 + cg) * 4]; \
        float4 w_z = *(const float4*)&s_W[((D_) * 48 + 16 + cg) * 4]; \
        float4 w_n = *(const float4*)&s_W[((D_) * 48 + 32 + cg) * 4]; \
        FMA4(ar[0], xv0.XC_, w_r); FMA4(az[0], xv0.XC_, w_z); FMA4(AN_[0], xv0.XC_, w_n); \
        FMA4(ar[1], xv1.XC_, w_r); FMA4(az[1], xv1.XC_, w_z); FMA4(AN_[1], xv1.XC_, w_n); }
#pragma unroll
    for (int dc = 0; dc < 4; ++dc) {   // ih part -> ani
        float4 xv0 = *(const float4*)&s_xh[(nl0    ) * 84 + dc * 4];
        float4 xv1 = *(const float4*)&s_xh[(nl0 + 4) * 84 + dc * 4];
        GSTEP(dc * 4 + 0, x, ani) GSTEP(dc * 4 + 1, y, ani)
        GSTEP(dc * 4 + 2, z, ani) GSTEP(dc * 4 + 3, w, ani)
    }
#pragma unroll 2
    for (int dc = 4; dc < 20; ++dc) {  // hh part -> anh
        float4 xv0 = *(const float4*)&s_xh[(nl0    ) * 84 + dc * 4];
        float4 xv1 = *(const float4*)&s_xh[(nl0 + 4) * 84 + dc * 4];
        GSTEP(dc * 4 + 0, x, anh) GSTEP(dc * 4 + 1, y, anh)
        GSTEP(dc * 4 + 2, z, anh) GSTEP(dc * 4 + 3, w, anh)
    }
#undef GSTEP

    // epilogue: GRU elementwise (h_old read from LDS)
    float b_r[4], b_z[4], b_ni[4], b_nh[4];
#pragma unroll
    for (int j = 0; j < 4; ++j) {
        int c = cg + 16 * j;
        b_r[j]  = bih[c] + bhh[c];
        b_z[j]  = bih[64 + c] + bhh[64 + c];
        b_ni[j] = bih[128 + c];
        b_nh[j] = bhh[128 + c];
    }
    float lb1 = lin1_b[cg];
    float hn[2][4];
#define EPI(M_, J_, COMP_) { \
        float rr = 1.0f / (1.0f + __expf(-(ar[M_].COMP_ + b_r[J_]))); \
        float zz = 1.0f / (1.0f + __expf(-(az[M_].COMP_ + b_z[J_]))); \
        float xx = fmaf(rr, anh[M_].COMP_ + b_nh[J_], ani[M_].COMP_ + b_ni[J_]); \
        float axx = fabsf(xx); float ee = __expf(-2.0f * axx); \
        float ncv = __builtin_copysignf((1.0f - ee) / (1.0f + ee), xx); \
        float hold = s_xh[(nl0 + 4 * (M_)) * 84 + 16 + cg + 16 * (J_)]; \
        hn[M_][J_] = fmaf(zz, hold - ncv, ncv); }
#pragma unroll
    for (int m = 0; m < 2; ++m) {
        EPI(m, 0, x) EPI(m, 1, y) EPI(m, 2, z) EPI(m, 3, w)
    }
#undef EPI
    __syncthreads();   // all h_old reads done
#pragma unroll
    for (int m = 0; m < 2; ++m) {
        int nl = nl0 + 4 * m;
#pragma unroll
        for (int j = 0; j < 4; ++j) s_xh[nl * 84 + 16 + cg + 16 * j] = hn[m][j];
    }
    __syncthreads();
    // fused lin1: out1_next = h_new @ w1 + b1
#pragma unroll
    for (int m = 0; m < 2; ++m) {
        int nl = nl0 + 4 * m;
        float acc = lb1;
#pragma unroll
        for (int d4 = 0; d4 < 16; ++d4) {
            float4 hv = *(const float4*)&s_xh[nl * 84 + 16 + d4 * 4];
            float4 wv = *(const float4*)&s_w1[cg * 68 + d4 * 4];
            acc = fmaf(hv.x, wv.x, fmaf(hv.y, wv.y, fmaf(hv.z, wv.z, fmaf(hv.w, wv.w, acc))));
        }
        out1[(size_t)(nb + nl) * 16 + cg] = acc;
    }
    // coalesced h writeback
    {
        float4* hdst = (float4*)(h + (size_t)nb * 64);
#pragma unroll
        for (int ii = 0; ii < 2; ++ii) {
            int i = tid + 256 * ii;
            int n = i >> 4, d4b = i & 15;
            hdst[i] = *(const float4*)&s_xh[n * 84 + 16 + d4b * 4];
        }
    }
}

// ---------------- final: y = h @ lin2_w ; pooled = segment_sum(y, batch) ----------------
__global__ __launch_bounds__(256) void k_final(const float* __restrict__ h, const float* __restrict__ w2,
                                               const int* __restrict__ batch, float* __restrict__ out) {
    int i = blockIdx.x * 4 + (threadIdx.x >> 6);
    int lane = threadIdx.x & 63;
    float v = h[(size_t)i * DIM + lane] * w2[lane];
#pragma unroll
    for (int off = 32; off > 0; off >>= 1) v += __shfl_down(v, off, 64);
    if (lane == 0) atomicAdd(&out[batch[i]], v);
}

extern "C" void kernel_launch(void* const* d_in, const int* in_sizes, int n_in,
                              void* d_out, int out_size, void* d_ws, size_t ws_size,
                              hipStream_t stream) {
    const float* x        = (const float*)d_in[0];
    const float* edge_attr= (const float*)d_in[1];
    const float* lin0_w   = (const float*)d_in[2];
    const float* lin0_b   = (const float*)d_in[3];
    const float* nn1_w    = (const float*)d_in[4];
    const float* nn1_b    = (const float*)d_in[5];
    const float* root_w   = (const float*)d_in[6];
    const float* conv_b   = (const float*)d_in[7];
    const float* gru_w_ih = (const float*)d_in[8];
    const float* gru_w_hh = (const float*)d_in[9];
    const float* gru_b_ih = (const float*)d_in[10];
    const float* gru_b_hh = (const float*)d_in[11];
    const float* lin1_w   = (const float*)d_in[12];
    const float* lin1_b   = (const float*)d_in[13];
    const float* lin2_w   = (const float*)d_in[14];
    const int*   ei       = (const int*)d_in[15];
    const int*   batch    = (const int*)d_in[16];
    float* out = (float*)d_out;

    // ws: h[N*64] | out1[N*16] | aggr[N*16] | inv_cnt[N] | Wt[4*80*192] | w1t[1024]
    char* ws = (char*)d_ws;
    float* h       = (float*)(ws);
    float* out1    = (float*)(ws + (size_t)N_NODES * DIM * 4);
    float* aggr    = (float*)(ws + (size_t)N_NODES * DIM * 4 + (size_t)N_NODES * DNN * 4);
    float* inv_cnt = (float*)(ws + (size_t)N_NODES * DIM * 4 + 2ull * N_NODES * DNN * 4);
    float* Wt      = inv_cnt + N_NODES;
    float* w1t     = Wt + 4 * 80 * 192;

    hipMemsetAsync(d_out, 0, (size_t)NG * 4, stream);
    hipMemsetAsync(inv_cnt, 0, (size_t)N_NODES * 4, stream);
    k_prep<<<240, 256, 0, stream>>>(gru_w_ih, gru_w_hh, lin1_w, Wt, w1t);
    k_degree<<<N_EDGES / 256, 256, 0, stream>>>(ei, inv_cnt);
    k_invcnt<<<N_NODES / 256, 256, 0, stream>>>(inv_cnt);
    k_init<<<N_NODES * DIM / 256, 256, 0, stream>>>(x, lin0_w, lin0_b, h);
    k_lin1<<<N_NODES / 64, 256, 0, stream>>>(h, lin1_w, lin1_b, out1, aggr);

    for (int it = 0; it < N_ITERS; ++it) {
        int j = it >> 1;   // GRU index (NL2 = 2)
        k_edge<<<2048, 256, 0, stream>>>(out1, edge_attr, ei, nn1_w, nn1_b, aggr);
        k_node<<<N_NODES / 32, 256, 0, stream>>>(out1, aggr, inv_cnt, h,
                                                 Wt + (size_t)j * 80 * 192, root_w, conv_b,
                                                 gru_b_ih + (size_t)j * 192,
                                                 gru_b_hh + (size_t)j * 192,
                                                 w1t, lin1_b);
    }
    k_final<<<N_NODES / 4, 256, 0, stream>>>(h, lin2_w, batch, out);
}

// Round 8
// 666.422 us; speedup vs baseline: 2.5246x; 1.7803x over previous
//
#include <hip/hip_runtime.h>
#include <hip/hip_bf16.h>

#define N_NODES 131072
#define N_EDGES 524288
#define F_IN 16
#define DIM 64
#define DNN 16
#define BK 4
#define NG 8192
#define N_ITERS 8   // NL1*NL2

typedef __bf16 bf16x8 __attribute__((ext_vector_type(8)));
typedef float f32x4 __attribute__((ext_vector_type(4)));

// ---------------- degree / inverse count ----------------
__global__ __launch_bounds__(256) void k_degree(const int* __restrict__ ei, float* __restrict__ cnt) {
    int e = blockIdx.x * 256 + threadIdx.x;
    atomicAdd(&cnt[ei[N_EDGES + e]], 1.0f);
}

__global__ __launch_bounds__(256) void k_invcnt(float* __restrict__ cnt) {
    int i = blockIdx.x * 256 + threadIdx.x;
    cnt[i] = 1.0f / fmaxf(cnt[i], 1.0f);
}

// ---------------- prep: build bf16 B-fragment weight tiles ----------------
// Wb[j][t][512]: t=0..35: ct=t/3,kk=t%3 (ct>=8 => n-gate HH: ih-rows zeroed);
// t=36..39: n-gate IH tiles (kk=0, hh-rows zeroed). Tile elem (kq,c16,jj) at
// (kq*16+c16)*8+jj holds W[k=kk*32+kq*8+jj][c=ct*16+c16]; K-row 80 = bias row
// (X[*][80]=1.0): r/z: bih+bhh, n-hh: bhh. rwb: o2 B-tile (root_w rows 0..15,
// rows 16..31 zero). w1b: lin1 B-tiles (K=64).
__global__ __launch_bounds__(256) void k_prep(const float* __restrict__ wih, const float* __restrict__ whh,
                                              const float* __restrict__ rw, const float* __restrict__ w1,
                                              const float* __restrict__ bih, const float* __restrict__ bhh,
                                              __bf16* __restrict__ Wb, __bf16* __restrict__ rwb,
                                              __bf16* __restrict__ w1b) {
    int idx = blockIdx.x * 256 + threadIdx.x;
    if (idx < 4 * 40 * 512) {
        int j = idx / 20480, r = idx % 20480;
        int t = r >> 9, e = r & 511;
        int jj = e & 7, c16 = (e >> 3) & 15, kq = e >> 7;
        int ct, kk; bool nih = false;
        if (t < 36) { ct = t / 3; kk = t % 3; } else { ct = 8 + (t - 36); kk = 0; nih = true; }
        int k = kk * 32 + kq * 8 + jj;
        int c = ct * 16 + c16;
        bool ngate = ct >= 8;
        float v = 0.f;
        if (nih) {
            if (k < 16) v = wih[((size_t)j * 192 + c) * 16 + k];
        } else {
            if (k < 16) v = ngate ? 0.f : wih[((size_t)j * 192 + c) * 16 + k];
            else if (k < 80) v = whh[((size_t)j * 192 + c) * 64 + (k - 16)];
            else if (k == 80) v = ngate ? bhh[j * 192 + c] : (bih[j * 192 + c] + bhh[j * 192 + c]);
        }
        Wb[idx] = (__bf16)v;
    } else if (idx < 4 * 40 * 512 + 512) {
        int e = idx - 4 * 40 * 512;
        int jj = e & 7, c16 = (e >> 3) & 15, kq = e >> 7;
        int k = kq * 8 + jj;
        rwb[e] = (__bf16)((k < 16) ? rw[k * 16 + c16] : 0.f);
    } else if (idx < 4 * 40 * 512 + 512 + 1024) {
        int e = idx - (4 * 40 * 512 + 512);
        int t2 = e >> 9, ee = e & 511;
        int jj = ee & 7, c16 = (ee >> 3) & 15, kq = ee >> 7;
        int k = t2 * 32 + kq * 8 + jj;
        w1b[e] = (__bf16)w1[k * 16 + c16];
    }
}

// ---------------- init: h = relu(x @ lin0_w + lin0_b) ----------------
__global__ __launch_bounds__(256) void k_init(const float* __restrict__ x, const float* __restrict__ w,
                                              const float* __restrict__ b, float* __restrict__ h) {
    __shared__ float s_w[F_IN * DIM];
    int tid = threadIdx.x;
    for (int idx = tid; idx < F_IN * DIM; idx += 256) s_w[idx] = w[idx];
    __syncthreads();
    int gid = blockIdx.x * 256 + tid;
    int i = gid >> 6;
    int c = gid & 63;
    int lane = tid & 63;
    float xv = x[i * F_IN + (lane & 15)];
    float acc = b[c];
#pragma unroll
    for (int k = 0; k < F_IN; ++k) acc += __shfl(xv, k, 64) * s_w[k * DIM + c];
    h[gid] = fmaxf(acc, 0.0f);
}

// ---------------- out1 = h @ lin1_w + lin1_b ; also zero aggr (once, pre-loop) ----------------
__global__ __launch_bounds__(256) void k_lin1(const float* __restrict__ h, const float* __restrict__ w,
                                              const float* __restrict__ b, float* __restrict__ out1,
                                              float* __restrict__ aggr) {
    __shared__ float s_h[64 * 68];
    int tid = threadIdx.x;
    int nb = blockIdx.x * 64;
    const float4* hp = (const float4*)(h + (size_t)nb * 64);
    for (int i = tid; i < 64 * 16; i += 256) {
        int n = i >> 4, q4 = i & 15;
        float4 v = hp[i];
        *(float4*)&s_h[n * 68 + q4 * 4] = v;
    }
    int ct = tid & 15;
    float wcol[64];
#pragma unroll
    for (int q = 0; q < 64; ++q) wcol[q] = w[q * 16 + ct];
    float bias = b[ct];
    ((float4*)(aggr + (size_t)nb * 16))[tid] = make_float4(0.f, 0.f, 0.f, 0.f);
    __syncthreads();
    int ng = tid >> 4;
#pragma unroll
    for (int rep = 0; rep < 4; ++rep) {
        int nl = ng + 16 * rep;
        float acc = bias;
#pragma unroll
        for (int q4 = 0; q4 < 16; ++q4) {
            float4 hv = *(const float4*)&s_h[nl * 68 + q4 * 4];
            acc = fmaf(hv.x, wcol[4 * q4 + 0], acc);
            acc = fmaf(hv.y, wcol[4 * q4 + 1], acc);
            acc = fmaf(hv.z, wcol[4 * q4 + 2], acc);
            acc = fmaf(hv.w, wcol[4 * q4 + 3], acc);
        }
        out1[(size_t)(nb + nl) * 16 + ct] = acc;
    }
}

// ---------------- edge: register-cached W columns, grid-stride over edges ----------------
__attribute__((amdgpu_waves_per_eu(2, 4)))
__global__ __launch_bounds__(256) void k_edge(const float* __restrict__ out1, const float* __restrict__ ea,
                                              const int* __restrict__ ei, const float* __restrict__ nn1w,
                                              const float* __restrict__ nn1b, float* __restrict__ aggr) {
    int tid = threadIdx.x;
    int o = tid & 15;
    float w0[16], w1[16], w2[16], w3[16], bs[16];
#pragma unroll
    for (int k = 0; k < 16; ++k) {
        int wi = k * 16 + o;
        bs[k] = nn1b[wi];
        w0[k] = nn1w[wi];
        w1[k] = nn1w[256 + wi];
        w2[k] = nn1w[512 + wi];
        w3[k] = nn1w[768 + wi];
    }
    int eg = blockIdx.x * 16 + (tid >> 4);
    int estride = gridDim.x * 16;
    for (int e = eg; e < N_EDGES; e += estride) {
        int src = ei[e];
        int dst = ei[N_EDGES + e];
        const float4* xp = (const float4*)(out1 + (size_t)src * 16);
        float4 x0 = xp[0], x1 = xp[1], x2 = xp[2], x3 = xp[3];
        float4 a = ((const float4*)ea)[e];
        float xa[16] = {x0.x, x0.y, x0.z, x0.w, x1.x, x1.y, x1.z, x1.w,
                        x2.x, x2.y, x2.z, x2.w, x3.x, x3.y, x3.z, x3.w};
        float msg = 0.f;
#pragma unroll
        for (int k = 0; k < 16; ++k) {
            float wv = bs[k];
            wv = fmaf(a.x, w0[k], wv);
            wv = fmaf(a.y, w1[k], wv);
            wv = fmaf(a.z, w2[k], wv);
            wv = fmaf(a.w, w3[k], wv);
            msg = fmaf(xa[k], wv, msg);
        }
        atomicAdd(&aggr[(size_t)dst * 16 + o], msg);
    }
}

// ---------------- node v5: MFMA GRU ----------------
// block = 64 nodes, 4 waves; wave w owns node-tile w (16 nodes).
// X[n][k] bf16 in s_X (stride 104): k 0..15 = o2 (out1 during o2-step), 16..79 = h,
// 80 = 1.0 (bias row), 81..103 = 0. Gates GEMM = 12 ct x 3 kk MFMAs + 4 n-ih.
// D-frag: row=node=(lane>>4)*4+reg, col=lane&15 -> epilogue thread-local.
__attribute__((amdgpu_waves_per_eu(2)))
__global__ __launch_bounds__(256) void k_node(
    float* __restrict__ out1, float* __restrict__ aggr, const float* __restrict__ inv_cnt,
    float* __restrict__ h, const __bf16* __restrict__ Wb, const __bf16* __restrict__ rwb,
    const __bf16* __restrict__ w1b, const float* __restrict__ conv_b,
    const float* __restrict__ bih, const float* __restrict__ lin1_b)
{
    __shared__ __align__(16) __bf16 s_X[64 * 104];   // 13312 B
    __shared__ __align__(16) __bf16 s_W[40 * 512];   // 40960 B
    __shared__ __align__(16) __bf16 s_rw[512];       //  1024 B
    __shared__ __align__(16) __bf16 s_w1[1024];      //  2048 B
    int tid = threadIdx.x;
    int nb = blockIdx.x * 64;
    int lane = tid & 63, w = tid >> 6;
    int c16 = lane & 15, lq = lane >> 4;

    // ---- stage W tiles (pure byte copy, 2560 x 16B)
    {
        const float4* src = (const float4*)Wb;
        float4* dst = (float4*)s_W;
#pragma unroll
        for (int i = 0; i < 10; ++i) dst[tid + 256 * i] = src[tid + 256 * i];
        if (tid < 64) ((float4*)s_rw)[tid] = ((const float4*)rwb)[tid];
        else if (tid < 192) ((float4*)s_w1)[tid - 64] = ((const float4*)w1b)[tid - 64];
    }
    // ---- stage h (f32->bf16) into s_X[n][16..79]
    {
        const float4* hsrc = (const float4*)(h + (size_t)nb * 64);
#pragma unroll
        for (int ii = 0; ii < 4; ++ii) {
            int i = tid + 256 * ii;
            float4 v = hsrc[i];
            int n = i >> 4, d4 = i & 15;
            __bf16* p = &s_X[n * 104 + 16 + d4 * 4];
            p[0] = (__bf16)v.x; p[1] = (__bf16)v.y; p[2] = (__bf16)v.z; p[3] = (__bf16)v.w;
        }
    }
    // ---- stage out1 (f32->bf16) into s_X[n][0..15]; pad cols 80..103 = {1,0,...}
    {
        float4 v = ((const float4*)(out1 + (size_t)nb * 16))[tid];
        int n = tid >> 2, k4 = tid & 3;
        __bf16* p = &s_X[n * 104 + k4 * 4];
        p[0] = (__bf16)v.x; p[1] = (__bf16)v.y; p[2] = (__bf16)v.z; p[3] = (__bf16)v.w;
        int c2 = (tid & 3) * 6;
#pragma unroll
        for (int q = 0; q < 6; ++q) {
            int col = 80 + c2 + q;
            s_X[n * 104 + col] = (col == 80) ? (__bf16)1.0f : (__bf16)0.0f;
        }
    }
    __syncthreads();

    // ---- o2 = out1 @ root_w + aggr*inv + conv_b  (rwb rows 16..31 = 0 mask the h cols)
    f32x4 co2;
    {
#pragma unroll
        for (int jr = 0; jr < 4; ++jr) {
            int node = nb + w * 16 + 4 * lq + jr;
            co2[jr] = fmaf(aggr[(size_t)node * 16 + c16], inv_cnt[node], conv_b[c16]);
            aggr[(size_t)node * 16 + c16] = 0.0f;   // zero for next iteration's k_edge
        }
        bf16x8 a0 = *(const bf16x8*)&s_X[(w * 16 + c16) * 104 + lq * 8];
        bf16x8 brw = *(const bf16x8*)&s_rw[lane * 8];
        co2 = __builtin_amdgcn_mfma_f32_16x16x32_bf16(a0, brw, co2, 0, 0, 0);
    }
    __syncthreads();
    {
#pragma unroll
        for (int jr = 0; jr < 4; ++jr)
            s_X[(w * 16 + 4 * lq + jr) * 104 + c16] = (__bf16)co2[jr];
    }
    __syncthreads();

    // ---- gates GEMM: acc[ct] ct=0..3 r, 4..7 z, 8..11 n-hh(+bnh); ani = n-ih
    f32x4 acc[12], ani4[4];
#pragma unroll
    for (int i = 0; i < 12; ++i) acc[i] = (f32x4){0.f, 0.f, 0.f, 0.f};
#pragma unroll
    for (int i = 0; i < 4; ++i) ani4[i] = (f32x4){0.f, 0.f, 0.f, 0.f};
    bf16x8 af[3];
#pragma unroll
    for (int kk = 0; kk < 3; ++kk)
        af[kk] = *(const bf16x8*)&s_X[(w * 16 + c16) * 104 + kk * 32 + lq * 8];
#pragma unroll
    for (int ct = 0; ct < 12; ++ct) {
#pragma unroll
        for (int kk = 0; kk < 3; ++kk) {
            bf16x8 bf = *(const bf16x8*)&s_W[(ct * 3 + kk) * 512 + lane * 8];
            acc[ct] = __builtin_amdgcn_mfma_f32_16x16x32_bf16(af[kk], bf, acc[ct], 0, 0, 0);
        }
    }
#pragma unroll
    for (int ct8 = 0; ct8 < 4; ++ct8) {
        bf16x8 bf = *(const bf16x8*)&s_W[(36 + ct8) * 512 + lane * 8];
        ani4[ct8] = __builtin_amdgcn_mfma_f32_16x16x32_bf16(af[0], bf, ani4[ct8], 0, 0, 0);
    }

    // ---- epilogue: GRU elementwise in D-layout (thread-local), h f32 from global
    float hn[4][4];
#pragma unroll
    for (int ct = 0; ct < 4; ++ct) {
        float bni = bih[128 + ct * 16 + c16];
#pragma unroll
        for (int jr = 0; jr < 4; ++jr) {
            int node = nb + w * 16 + 4 * lq + jr;
            float hold = h[(size_t)node * 64 + ct * 16 + c16];
            float rr = 1.f / (1.f + __expf(-acc[ct][jr]));
            float zz = 1.f / (1.f + __expf(-acc[4 + ct][jr]));
            float xx = fmaf(rr, acc[8 + ct][jr], ani4[ct][jr] + bni);
            float ax = fabsf(xx);
            float ee = __expf(-2.f * ax);
            float ncv = __builtin_copysignf((1.f - ee) / (1.f + ee), xx);
            float hv = fmaf(zz, hold - ncv, ncv);
            hn[ct][jr] = hv;
            h[(size_t)node * 64 + ct * 16 + c16] = hv;
        }
    }
    __syncthreads();
#pragma unroll
    for (int ct = 0; ct < 4; ++ct)
#pragma unroll
        for (int jr = 0; jr < 4; ++jr)
            s_X[(w * 16 + 4 * lq + jr) * 104 + 16 + ct * 16 + c16] = (__bf16)hn[ct][jr];
    __syncthreads();

    // ---- fused lin1: out1 = h_new @ w1 + b1 (K=64 from s_X[*][16..79])
    f32x4 o1acc = (f32x4){0.f, 0.f, 0.f, 0.f};
#pragma unroll
    for (int kk = 0; kk < 2; ++kk) {
        bf16x8 a = *(const bf16x8*)&s_X[(w * 16 + c16) * 104 + 16 + kk * 32 + lq * 8];
        bf16x8 b = *(const bf16x8*)&s_w1[kk * 512 + lane * 8];
        o1acc = __builtin_amdgcn_mfma_f32_16x16x32_bf16(a, b, o1acc, 0, 0, 0);
    }
    float lb = lin1_b[c16];
#pragma unroll
    for (int jr = 0; jr < 4; ++jr) {
        int node = nb + w * 16 + 4 * lq + jr;
        out1[(size_t)node * 16 + c16] = o1acc[jr] + lb;
    }
}

// ---------------- final: y = h @ lin2_w ; pooled = segment_sum(y, batch) ----------------
__global__ __launch_bounds__(256) void k_final(const float* __restrict__ h, const float* __restrict__ w2,
                                               const int* __restrict__ batch, float* __restrict__ out) {
    int i = blockIdx.x * 4 + (threadIdx.x >> 6);
    int lane = threadIdx.x & 63;
    float v = h[(size_t)i * DIM + lane] * w2[lane];
#pragma unroll
    for (int off = 32; off > 0; off >>= 1) v += __shfl_down(v, off, 64);
    if (lane == 0) atomicAdd(&out[batch[i]], v);
}

extern "C" void kernel_launch(void* const* d_in, const int* in_sizes, int n_in,
                              void* d_out, int out_size, void* d_ws, size_t ws_size,
                              hipStream_t stream) {
    const float* x        = (const float*)d_in[0];
    const float* edge_attr= (const float*)d_in[1];
    const float* lin0_w   = (const float*)d_in[2];
    const float* lin0_b   = (const float*)d_in[3];
    const float* nn1_w    = (const float*)d_in[4];
    const float* nn1_b    = (const float*)d_in[5];
    const float* root_w   = (const float*)d_in[6];
    const float* conv_b   = (const float*)d_in[7];
    const float* gru_w_ih = (const float*)d_in[8];
    const float* gru_w_hh = (const float*)d_in[9];
    const float* gru_b_ih = (const float*)d_in[10];
    const float* gru_b_hh = (const float*)d_in[11];
    const float* lin1_w   = (const float*)d_in[12];
    const float* lin1_b   = (const float*)d_in[13];
    const float* lin2_w   = (const float*)d_in[14];
    const int*   ei       = (const int*)d_in[15];
    const int*   batch    = (const int*)d_in[16];
    float* out = (float*)d_out;

    // ws: h[N*64] | out1[N*16] | aggr[N*16] | inv_cnt[N] | Wb bf16[4*40*512] | rwb[512] | w1b[1024]
    char* ws = (char*)d_ws;
    float* h       = (float*)(ws);
    float* out1    = (float*)(ws + (size_t)N_NODES * DIM * 4);
    float* aggr    = (float*)(ws + (size_t)N_NODES * DIM * 4 + (size_t)N_NODES * DNN * 4);
    float* inv_cnt = (float*)(ws + (size_t)N_NODES * DIM * 4 + 2ull * N_NODES * DNN * 4);
    __bf16* Wb     = (__bf16*)(inv_cnt + N_NODES);
    __bf16* rwb    = Wb + 4 * 40 * 512;
    __bf16* w1b    = rwb + 512;

    hipMemsetAsync(d_out, 0, (size_t)NG * 4, stream);
    hipMemsetAsync(inv_cnt, 0, (size_t)N_NODES * 4, stream);
    k_prep<<<326, 256, 0, stream>>>(gru_w_ih, gru_w_hh, root_w, lin1_w, gru_b_ih, gru_b_hh,
                                    Wb, rwb, w1b);
    k_degree<<<N_EDGES / 256, 256, 0, stream>>>(ei, inv_cnt);
    k_invcnt<<<N_NODES / 256, 256, 0, stream>>>(inv_cnt);
    k_init<<<N_NODES * DIM / 256, 256, 0, stream>>>(x, lin0_w, lin0_b, h);
    k_lin1<<<N_NODES / 64, 256, 0, stream>>>(h, lin1_w, lin1_b, out1, aggr);

    for (int it = 0; it < N_ITERS; ++it) {
        int j = it >> 1;   // GRU index (NL2 = 2)
        k_edge<<<2048, 256, 0, stream>>>(out1, edge_attr, ei, nn1_w, nn1_b, aggr);
        k_node<<<N_NODES / 64, 256, 0, stream>>>(out1, aggr, inv_cnt, h,
                                                 Wb + (size_t)j * 40 * 512, rwb, w1b,
                                                 conv_b, gru_b_ih + (size_t)j * 192, lin1_b);
    }
    k_final<<<N_NODES / 4, 256, 0, stream>>>(h, lin2_w, batch, out);
}